// Round 7
// baseline (220.806 us; speedup 1.0000x reference)
//
#include <hip/hip_runtime.h>
#include <hip/hip_bf16.h>

#define N_NODES 50000
#define N_EDGES 800000
#define D 128
#define NB_SCAN ((N_NODES + 255) / 256)  // 196

typedef short bf16x8 __attribute__((ext_vector_type(8)));
typedef float f32x4 __attribute__((ext_vector_type(4)));

__device__ __forceinline__ unsigned int bf16u(float f) {
  __hip_bfloat16 b = __float2bfloat16(f);
  return (unsigned int)*reinterpret_cast<unsigned short*>(&b);
}

// ---------------------------------------------------------------------------
// Fused LN+ReLU+mask + MFMA GEMM:
//   h = relu(LN(x))*mask (bf16, in-register only)
//   [g | r](permuted cols) = h @ [w_l | w_r]^T (+ b_l on the r half)
// Block = 4 waves = 64 nodes x 256 outs; grid 782.
// LN: A-frag layout is quad-split per node row (lanes with equal lm across the
// 4 quads hold disjoint 32-col chunks) -> stats via shfl_xor(16|32).
// B: w_l/w_r rows are k-contiguous; cast f32->bf16 while staging LDS frags.
// Store layout s = (col&15)*8 + (col>>4); agg un-permutes in its epilogue.
// Also: first 196 blocks zero deg[] (replaces a memset launch).
// ---------------------------------------------------------------------------
__global__ __launch_bounds__(256) void gemm_kernel(
    const float* __restrict__ x, const float* __restrict__ mask,
    const float* __restrict__ gamma, const float* __restrict__ beta,
    const float* __restrict__ w_l, const float* __restrict__ w_r,
    const float* __restrict__ b_l, unsigned int* __restrict__ gb,
    float* __restrict__ rp, int* __restrict__ deg) {
  __shared__ unsigned short Bs[64 * 64 * 8];  // 64 frags x 64 lanes x 8 bf16
  const int t = threadIdx.x;
  const int w = t >> 6;
  const int l = t & 63;
  const int lm = l & 15;
  const int quad = l >> 4;
  const int nb = blockIdx.x * 64;

  // Fold deg-zeroing into the grid (runs before hist on the same stream).
  if (blockIdx.x < NB_SCAN) {
    const int i = blockIdx.x * 256 + t;
    if (i < N_NODES) deg[i] = 0;
  }

  // Stage B into fragment-ordered LDS, casting f32->bf16 on the fly.
  // frag fid=(sub,ch) lane l holds row sub*16+lm (w_l for sub<8, else w_r),
  // cols ch*32 + quad*8 .. +8.
#pragma unroll
  for (int i = 0; i < 16; ++i) {
    const int fid = w * 16 + i;
    const int sub = fid >> 2;
    const int ch = fid & 3;
    const float* srcw = (sub < 8) ? (w_l + (size_t)(sub * 16 + lm) * D)
                                  : (w_r + (size_t)((sub - 8) * 16 + lm) * D);
    const float4 a = *(const float4*)(srcw + ch * 32 + quad * 8);
    const float4 b = *(const float4*)(srcw + ch * 32 + quad * 8 + 4);
    uint4 v;
    v.x = (bf16u(a.y) << 16) | bf16u(a.x);
    v.y = (bf16u(a.w) << 16) | bf16u(a.z);
    v.z = (bf16u(b.y) << 16) | bf16u(b.x);
    v.w = (bf16u(b.w) << 16) | bf16u(b.z);
    *(uint4*)(Bs + ((size_t)fid * 64 + l) * 8) = v;
  }

  // ---- LayerNorm in registers ----
  int anode = nb + w * 16 + lm;
  if (anode >= N_NODES) anode = N_NODES - 1;  // clamped read; stores guarded
  const float* xrow = x + (size_t)anode * D;
  float xv[32];
  float s = 0.f, q = 0.f;
#pragma unroll
  for (int ch = 0; ch < 4; ++ch) {
    const float4 a = *(const float4*)(xrow + ch * 32 + quad * 8);
    const float4 b = *(const float4*)(xrow + ch * 32 + quad * 8 + 4);
    xv[ch * 8 + 0] = a.x; xv[ch * 8 + 1] = a.y;
    xv[ch * 8 + 2] = a.z; xv[ch * 8 + 3] = a.w;
    xv[ch * 8 + 4] = b.x; xv[ch * 8 + 5] = b.y;
    xv[ch * 8 + 6] = b.z; xv[ch * 8 + 7] = b.w;
    s += (a.x + a.y) + (a.z + a.w) + (b.x + b.y) + (b.z + b.w);
    q += a.x * a.x + a.y * a.y + a.z * a.z + a.w * a.w +
         b.x * b.x + b.y * b.y + b.z * b.z + b.w * b.w;
  }
  s += __shfl_xor(s, 16);
  s += __shfl_xor(s, 32);
  q += __shfl_xor(q, 16);
  q += __shfl_xor(q, 32);
  const float mean = s * (1.0f / 128.0f);
  const float var = q * (1.0f / 128.0f) - mean * mean;
  const float rs = rsqrtf(var + 1e-5f);

  const float* mrow = mask + (size_t)anode * D;
  bf16x8 af[4];
#pragma unroll
  for (int ch = 0; ch < 4; ++ch) {
    const int c0 = ch * 32 + quad * 8;
    const float4 g0 = *(const float4*)(gamma + c0);
    const float4 g1 = *(const float4*)(gamma + c0 + 4);
    const float4 b0 = *(const float4*)(beta + c0);
    const float4 b1 = *(const float4*)(beta + c0 + 4);
    const float4 m0 = *(const float4*)(mrow + c0);
    const float4 m1 = *(const float4*)(mrow + c0 + 4);
    const float gv[8] = {g0.x, g0.y, g0.z, g0.w, g1.x, g1.y, g1.z, g1.w};
    const float bv[8] = {b0.x, b0.y, b0.z, b0.w, b1.x, b1.y, b1.z, b1.w};
    const float mv[8] = {m0.x, m0.y, m0.z, m0.w, m1.x, m1.y, m1.z, m1.w};
#pragma unroll
    for (int j = 0; j < 8; ++j) {
      const float hv =
          fmaxf((xv[ch * 8 + j] - mean) * rs * gv[j] + bv[j], 0.0f) * mv[j];
      af[ch][j] = (short)bf16u(hv);
    }
  }
  __syncthreads();

  f32x4 acc[16];
#pragma unroll
  for (int sub = 0; sub < 16; ++sub) acc[sub] = (f32x4){0.f, 0.f, 0.f, 0.f};
  const bf16x8* BsF = (const bf16x8*)Bs;
#pragma unroll
  for (int sub = 0; sub < 16; ++sub)
#pragma unroll
    for (int ch = 0; ch < 4; ++ch)
      acc[sub] = __builtin_amdgcn_mfma_f32_16x16x32_bf16(
          af[ch], BsF[(sub * 4 + ch) * 64 + l], acc[sub], 0, 0, 0);

  // Epilogue: bias values this lane needs: b_l[j*16 + lm], j=0..7.
  float blv[8];
#pragma unroll
  for (int j = 0; j < 8; ++j) blv[j] = b_l[j * 16 + lm];

  const int node0 = nb + w * 16 + quad * 4;
#pragma unroll
  for (int reg = 0; reg < 4; ++reg) {
    const int node = node0 + reg;
    if (node < N_NODES) {
      uint4 p;
      p.x = (bf16u(acc[1][reg]) << 16) | bf16u(acc[0][reg]);
      p.y = (bf16u(acc[3][reg]) << 16) | bf16u(acc[2][reg]);
      p.z = (bf16u(acc[5][reg]) << 16) | bf16u(acc[4][reg]);
      p.w = (bf16u(acc[7][reg]) << 16) | bf16u(acc[6][reg]);
      ((uint4*)gb)[(size_t)node * 16 + lm] = p;
      float4 q0, q1;
      q0.x = acc[8][reg] + blv[0];
      q0.y = acc[9][reg] + blv[1];
      q0.z = acc[10][reg] + blv[2];
      q0.w = acc[11][reg] + blv[3];
      q1.x = acc[12][reg] + blv[4];
      q1.y = acc[13][reg] + blv[5];
      q1.z = acc[14][reg] + blv[6];
      q1.w = acc[15][reg] + blv[7];
      ((float4*)rp)[(size_t)node * 32 + lm * 2 + 0] = q0;
      ((float4*)rp)[(size_t)node * 32 + lm * 2 + 1] = q1;
    }
  }
}

// ---------------------------------------------------------------------------
// CSR build: degree histogram (capturing per-edge rank) -> 2-level scan
// (final offsets computed on the fly by consumers) -> atomic-free scatter.
// ---------------------------------------------------------------------------
__global__ __launch_bounds__(256) void hist_kernel(const int* __restrict__ ei,
                                                   int* __restrict__ deg,
                                                   int* __restrict__ rank) {
  const int e = (blockIdx.x * 256 + threadIdx.x) * 4;
  if (e + 3 < N_EDGES) {
    const int4 d4 = *(const int4*)(ei + N_EDGES + e);
    int4 r4;
    r4.x = atomicAdd(&deg[d4.x], 1);
    r4.y = atomicAdd(&deg[d4.y], 1);
    r4.z = atomicAdd(&deg[d4.z], 1);
    r4.w = atomicAdd(&deg[d4.w], 1);
    *(int4*)(rank + e) = r4;
  } else {
    for (int k = e; k < N_EDGES; ++k)
      rank[k] = atomicAdd(&deg[ei[N_EDGES + k]], 1);
  }
}

__global__ __launch_bounds__(256) void scan1_kernel(
    const int* __restrict__ deg, int* __restrict__ offL1,
    int* __restrict__ partial) {
  __shared__ int sm[256];
  const int t = threadIdx.x;
  const int i = blockIdx.x * 256 + t;
  const int v = (i < N_NODES) ? deg[i] : 0;
  sm[t] = v;
  __syncthreads();
#pragma unroll
  for (int ofs = 1; ofs < 256; ofs <<= 1) {
    int x = sm[t];
    if (t >= ofs) x += sm[t - ofs];
    __syncthreads();
    sm[t] = x;
    __syncthreads();
  }
  if (i < N_NODES) offL1[i] = sm[t] - v;
  if (t == 255) partial[blockIdx.x] = sm[255];
}

__global__ __launch_bounds__(256) void scan2_kernel(int* __restrict__ partial) {
  __shared__ int sm[256];
  const int t = threadIdx.x;
  const int v = (t < NB_SCAN) ? partial[t] : 0;
  sm[t] = v;
  __syncthreads();
#pragma unroll
  for (int ofs = 1; ofs < 256; ofs <<= 1) {
    int x = sm[t];
    if (t >= ofs) x += sm[t - ofs];
    __syncthreads();
    sm[t] = x;
    __syncthreads();
  }
  if (t < NB_SCAN) partial[t] = sm[t] - v;
}

__global__ __launch_bounds__(256) void scatter_kernel(
    const int* __restrict__ ei, const int* __restrict__ offL1,
    const int* __restrict__ partial, const int* __restrict__ rank,
    int* __restrict__ csr) {
  const int e = (blockIdx.x * 256 + threadIdx.x) * 4;
  if (e + 3 < N_EDGES) {
    const int4 s4 = *(const int4*)(ei + e);
    const int4 d4 = *(const int4*)(ei + N_EDGES + e);
    const int4 r4 = *(const int4*)(rank + e);
    csr[offL1[d4.x] + partial[d4.x >> 8] + r4.x] = s4.x;
    csr[offL1[d4.y] + partial[d4.y >> 8] + r4.y] = s4.y;
    csr[offL1[d4.z] + partial[d4.z >> 8] + r4.z] = s4.z;
    csr[offL1[d4.w] + partial[d4.w >> 8] + r4.w] = s4.w;
  } else {
    for (int k = e; k < N_EDGES; ++k) {
      const int dst = ei[N_EDGES + k];
      csr[offL1[dst] + partial[dst >> 8] + rank[k]] = ei[k];
    }
  }
}

// ---------------------------------------------------------------------------
// Mean-aggregate bf16 g rows (permuted layout) per dst node, + r -> out.
// One wave per node; 4 rows per vmem instruction (quarter-wave x uint4).
// Lane c's uint4 chunk holds cols {j*16+c, j=0..7}; epilogue un-permutes.
// ---------------------------------------------------------------------------
#define ACC8(v)                                     \
  do {                                              \
    acc[0] += __uint_as_float((v).x << 16);         \
    acc[1] += __uint_as_float((v).x & 0xffff0000u); \
    acc[2] += __uint_as_float((v).y << 16);         \
    acc[3] += __uint_as_float((v).y & 0xffff0000u); \
    acc[4] += __uint_as_float((v).z << 16);         \
    acc[5] += __uint_as_float((v).z & 0xffff0000u); \
    acc[6] += __uint_as_float((v).w << 16);         \
    acc[7] += __uint_as_float((v).w & 0xffff0000u); \
  } while (0)

__global__ __launch_bounds__(256) void agg_kernel(
    const int* __restrict__ offL1, const int* __restrict__ partial,
    const int* __restrict__ csr, const unsigned int* __restrict__ gb,
    const float* __restrict__ rp, float* __restrict__ out) {
  const int l = threadIdx.x & 63;
  const int q = l >> 4;  // row within group of 4
  const int c = l & 15;  // 16B chunk within the 256B bf16 row
  const int n = blockIdx.x * 4 + (threadIdx.x >> 6);
  const int s = offL1[n] + partial[n >> 8];
  const int e = (n + 1 < N_NODES) ? offL1[n + 1] + partial[(n + 1) >> 8]
                                  : N_EDGES;
  const uint4* g4 = (const uint4*)gb;
  float acc[8];
#pragma unroll
  for (int k = 0; k < 8; ++k) acc[k] = 0.0f;
  for (int base = s; base < e; base += 64) {
    const int cnt = min(e - base, 64);
    int idx = (l < cnt) ? csr[base + l] : 0;
    int j = 0;
    for (; j + 16 <= cnt; j += 16) {
      const int i0 = __shfl(idx, j + 0 + q);
      const int i1 = __shfl(idx, j + 4 + q);
      const int i2 = __shfl(idx, j + 8 + q);
      const int i3 = __shfl(idx, j + 12 + q);
      const uint4 v0 = g4[(size_t)i0 * 16 + c];
      const uint4 v1 = g4[(size_t)i1 * 16 + c];
      const uint4 v2 = g4[(size_t)i2 * 16 + c];
      const uint4 v3 = g4[(size_t)i3 * 16 + c];
      ACC8(v0);
      ACC8(v1);
      ACC8(v2);
      ACC8(v3);
    }
    for (; j + 4 <= cnt; j += 4) {
      const int i0 = __shfl(idx, j + q);
      const uint4 v0 = g4[(size_t)i0 * 16 + c];
      ACC8(v0);
    }
    if (j < cnt) {
      const int rem = cnt - j;  // 1..3 leftover rows
      const int i0 = __shfl(idx, j + min(q, rem - 1));
      if (q < rem) {
        const uint4 v0 = g4[(size_t)i0 * 16 + c];
        ACC8(v0);
      }
    }
  }
#pragma unroll
  for (int k = 0; k < 8; ++k) {
    acc[k] += __shfl_xor(acc[k], 16);
    acc[k] += __shfl_xor(acc[k], 32);
  }
  if (l < 16) {
    const float inv = 1.0f / fmaxf((float)(e - s), 1.0f);
    const float4 rp0 = ((const float4*)rp)[(size_t)n * 32 + c * 2 + 0];
    const float4 rp1 = ((const float4*)rp)[(size_t)n * 32 + c * 2 + 1];
    float* o = out + (size_t)n * D + c;  // col j*16 + c, stride-16 stores
    o[0]   = fmaf(acc[0], inv, rp0.x);
    o[16]  = fmaf(acc[1], inv, rp0.y);
    o[32]  = fmaf(acc[2], inv, rp0.z);
    o[48]  = fmaf(acc[3], inv, rp0.w);
    o[64]  = fmaf(acc[4], inv, rp1.x);
    o[80]  = fmaf(acc[5], inv, rp1.y);
    o[96]  = fmaf(acc[6], inv, rp1.z);
    o[112] = fmaf(acc[7], inv, rp1.w);
  }
}

// ---------------------------------------------------------------------------
extern "C" void kernel_launch(void* const* d_in, const int* in_sizes, int n_in,
                              void* d_out, int out_size, void* d_ws,
                              size_t ws_size, hipStream_t stream) {
  const float* x = (const float*)d_in[0];
  const int* ei = (const int*)d_in[1];  // [2,E] flat: src [0,E), dst [E,2E)
  const float* mask = (const float*)d_in[2];
  const float* gamma = (const float*)d_in[3];
  const float* beta = (const float*)d_in[4];
  const float* w_l = (const float*)d_in[5];
  const float* b_l = (const float*)d_in[6];
  const float* w_r = (const float*)d_in[7];
  float* out = (float*)d_out;

  char* ws = (char*)d_ws;
  size_t off = 0;
  auto alloc = [&](size_t bytes) {
    char* p = ws + off;
    off += (bytes + 255) & ~(size_t)255;
    return p;
  };
  unsigned int* gb =
      (unsigned int*)alloc((size_t)N_NODES * D * sizeof(unsigned short));
  float* rp = (float*)alloc((size_t)N_NODES * D * sizeof(float));
  int* deg = (int*)alloc((size_t)N_NODES * sizeof(int));
  int* offL1 = (int*)alloc((size_t)N_NODES * sizeof(int));
  int* partial = (int*)alloc((size_t)NB_SCAN * sizeof(int));
  int* rank = (int*)alloc((size_t)N_EDGES * sizeof(int));
  int* csr = (int*)alloc((size_t)N_EDGES * sizeof(int));

  gemm_kernel<<<(N_NODES + 63) / 64, 256, 0, stream>>>(
      x, mask, gamma, beta, w_l, w_r, b_l, gb, rp, deg);
  hist_kernel<<<(N_EDGES / 4 + 255) / 256, 256, 0, stream>>>(ei, deg, rank);
  scan1_kernel<<<NB_SCAN, 256, 0, stream>>>(deg, offL1, partial);
  scan2_kernel<<<1, 256, 0, stream>>>(partial);
  scatter_kernel<<<(N_EDGES / 4 + 255) / 256, 256, 0, stream>>>(
      ei, offL1, partial, rank, csr);
  agg_kernel<<<N_NODES / 4, 256, 0, stream>>>(offL1, partial, csr, gb, rp,
                                              out);
}

// Round 8
// 208.675 us; speedup vs baseline: 1.0581x; 1.0581x over previous
//
#include <hip/hip_runtime.h>
#include <hip/hip_bf16.h>

#define N_NODES 50000
#define N_EDGES 800000
#define D 128
#define NB_SCAN ((N_NODES + 255) / 256)  // 196
#define NB_GEMM ((N_NODES + 63) / 64)    // 782
#define EDGES_PER_GEMM_BLOCK 1024        // 782*1024 >= 800000

typedef short bf16x8 __attribute__((ext_vector_type(8)));
typedef float f32x4 __attribute__((ext_vector_type(4)));

__device__ __forceinline__ unsigned int bf16u(float f) {
  __hip_bfloat16 b = __float2bfloat16(f);
  return (unsigned int)*reinterpret_cast<unsigned short*>(&b);
}

// ---------------------------------------------------------------------------
// Zero deg[] and the scan done-counter (graph-safe: runs every call).
// ---------------------------------------------------------------------------
__global__ __launch_bounds__(256) void zero_kernel(int* __restrict__ deg,
                                                   int* __restrict__ done) {
  const int i = blockIdx.x * 256 + threadIdx.x;
  if (i < N_NODES) deg[i] = 0;
  if (i == 0) *done = 0;
}

// ---------------------------------------------------------------------------
// Fused LN+ReLU+mask + MFMA GEMM + edge-histogram:
//   h = relu(LN(x))*mask (bf16, in-register only)
//   [g | r](permuted cols) = h @ [w_l | w_r]^T (+ b_l on the r half)
//   plus: each block histograms a 1024-edge slice (deg atomics + rank),
//   overlapped with the GEMM's memory/MFMA time.
// Block = 4 waves = 64 nodes x 256 outs; grid 782.
// Store layout s = (col&15)*8 + (col>>4); agg un-permutes in its epilogue.
// ---------------------------------------------------------------------------
__global__ __launch_bounds__(256) void gemm_kernel(
    const float* __restrict__ x, const float* __restrict__ mask,
    const float* __restrict__ gamma, const float* __restrict__ beta,
    const float* __restrict__ w_l, const float* __restrict__ w_r,
    const float* __restrict__ b_l, unsigned int* __restrict__ gb,
    float* __restrict__ rp, const int* __restrict__ ei,
    int* __restrict__ deg, int* __restrict__ rank) {
  __shared__ unsigned short Bs[64 * 64 * 8];  // 64 frags x 64 lanes x 8 bf16
  const int t = threadIdx.x;
  const int w = t >> 6;
  const int l = t & 63;
  const int lm = l & 15;
  const int quad = l >> 4;
  const int nb = blockIdx.x * 64;

  // ---- fused histogram slice (deg was zeroed by zero_kernel) ----
  {
    const int e = blockIdx.x * EDGES_PER_GEMM_BLOCK + t * 4;
    if (e + 3 < N_EDGES) {
      const int4 d4 = *(const int4*)(ei + N_EDGES + e);
      int4 r4;
      r4.x = atomicAdd(&deg[d4.x], 1);
      r4.y = atomicAdd(&deg[d4.y], 1);
      r4.z = atomicAdd(&deg[d4.z], 1);
      r4.w = atomicAdd(&deg[d4.w], 1);
      *(int4*)(rank + e) = r4;
    } else {
      for (int k = e; k < N_EDGES; ++k)
        rank[k] = atomicAdd(&deg[ei[N_EDGES + k]], 1);
    }
  }

  // Stage B into fragment-ordered LDS, casting f32->bf16 on the fly.
#pragma unroll
  for (int i = 0; i < 16; ++i) {
    const int fid = w * 16 + i;
    const int sub = fid >> 2;
    const int ch = fid & 3;
    const float* srcw = (sub < 8) ? (w_l + (size_t)(sub * 16 + lm) * D)
                                  : (w_r + (size_t)((sub - 8) * 16 + lm) * D);
    const float4 a = *(const float4*)(srcw + ch * 32 + quad * 8);
    const float4 b = *(const float4*)(srcw + ch * 32 + quad * 8 + 4);
    uint4 v;
    v.x = (bf16u(a.y) << 16) | bf16u(a.x);
    v.y = (bf16u(a.w) << 16) | bf16u(a.z);
    v.z = (bf16u(b.y) << 16) | bf16u(b.x);
    v.w = (bf16u(b.w) << 16) | bf16u(b.z);
    *(uint4*)(Bs + ((size_t)fid * 64 + l) * 8) = v;
  }

  // ---- LayerNorm in registers ----
  int anode = nb + w * 16 + lm;
  if (anode >= N_NODES) anode = N_NODES - 1;  // clamped read; stores guarded
  const float* xrow = x + (size_t)anode * D;
  float xv[32];
  float s = 0.f, q = 0.f;
#pragma unroll
  for (int ch = 0; ch < 4; ++ch) {
    const float4 a = *(const float4*)(xrow + ch * 32 + quad * 8);
    const float4 b = *(const float4*)(xrow + ch * 32 + quad * 8 + 4);
    xv[ch * 8 + 0] = a.x; xv[ch * 8 + 1] = a.y;
    xv[ch * 8 + 2] = a.z; xv[ch * 8 + 3] = a.w;
    xv[ch * 8 + 4] = b.x; xv[ch * 8 + 5] = b.y;
    xv[ch * 8 + 6] = b.z; xv[ch * 8 + 7] = b.w;
    s += (a.x + a.y) + (a.z + a.w) + (b.x + b.y) + (b.z + b.w);
    q += a.x * a.x + a.y * a.y + a.z * a.z + a.w * a.w +
         b.x * b.x + b.y * b.y + b.z * b.z + b.w * b.w;
  }
  s += __shfl_xor(s, 16);
  s += __shfl_xor(s, 32);
  q += __shfl_xor(q, 16);
  q += __shfl_xor(q, 32);
  const float mean = s * (1.0f / 128.0f);
  const float var = q * (1.0f / 128.0f) - mean * mean;
  const float rs = rsqrtf(var + 1e-5f);

  const float* mrow = mask + (size_t)anode * D;
  bf16x8 af[4];
#pragma unroll
  for (int ch = 0; ch < 4; ++ch) {
    const int c0 = ch * 32 + quad * 8;
    const float4 g0 = *(const float4*)(gamma + c0);
    const float4 g1 = *(const float4*)(gamma + c0 + 4);
    const float4 b0 = *(const float4*)(beta + c0);
    const float4 b1 = *(const float4*)(beta + c0 + 4);
    const float4 m0 = *(const float4*)(mrow + c0);
    const float4 m1 = *(const float4*)(mrow + c0 + 4);
    const float gv[8] = {g0.x, g0.y, g0.z, g0.w, g1.x, g1.y, g1.z, g1.w};
    const float bv[8] = {b0.x, b0.y, b0.z, b0.w, b1.x, b1.y, b1.z, b1.w};
    const float mv[8] = {m0.x, m0.y, m0.z, m0.w, m1.x, m1.y, m1.z, m1.w};
#pragma unroll
    for (int j = 0; j < 8; ++j) {
      const float hv =
          fmaxf((xv[ch * 8 + j] - mean) * rs * gv[j] + bv[j], 0.0f) * mv[j];
      af[ch][j] = (short)bf16u(hv);
    }
  }
  __syncthreads();

  f32x4 acc[16];
#pragma unroll
  for (int sub = 0; sub < 16; ++sub) acc[sub] = (f32x4){0.f, 0.f, 0.f, 0.f};
  const bf16x8* BsF = (const bf16x8*)Bs;
#pragma unroll
  for (int sub = 0; sub < 16; ++sub)
#pragma unroll
    for (int ch = 0; ch < 4; ++ch)
      acc[sub] = __builtin_amdgcn_mfma_f32_16x16x32_bf16(
          af[ch], BsF[(sub * 4 + ch) * 64 + l], acc[sub], 0, 0, 0);

  // Epilogue: bias values this lane needs: b_l[j*16 + lm], j=0..7.
  float blv[8];
#pragma unroll
  for (int j = 0; j < 8; ++j) blv[j] = b_l[j * 16 + lm];

  const int node0 = nb + w * 16 + quad * 4;
#pragma unroll
  for (int reg = 0; reg < 4; ++reg) {
    const int node = node0 + reg;
    if (node < N_NODES) {
      uint4 p;
      p.x = (bf16u(acc[1][reg]) << 16) | bf16u(acc[0][reg]);
      p.y = (bf16u(acc[3][reg]) << 16) | bf16u(acc[2][reg]);
      p.z = (bf16u(acc[5][reg]) << 16) | bf16u(acc[4][reg]);
      p.w = (bf16u(acc[7][reg]) << 16) | bf16u(acc[6][reg]);
      ((uint4*)gb)[(size_t)node * 16 + lm] = p;
      float4 q0, q1;
      q0.x = acc[8][reg] + blv[0];
      q0.y = acc[9][reg] + blv[1];
      q0.z = acc[10][reg] + blv[2];
      q0.w = acc[11][reg] + blv[3];
      q1.x = acc[12][reg] + blv[4];
      q1.y = acc[13][reg] + blv[5];
      q1.z = acc[14][reg] + blv[6];
      q1.w = acc[15][reg] + blv[7];
      ((float4*)rp)[(size_t)node * 32 + lm * 2 + 0] = q0;
      ((float4*)rp)[(size_t)node * 32 + lm * 2 + 1] = q1;
    }
  }
}

// ---------------------------------------------------------------------------
// Fused 2-level scan: per-block exclusive scan of deg + block totals; the
// LAST block to finish scans the 196 totals (device-scope release/acquire
// per G16 — per-XCD L2s are not cross-coherent).
// ---------------------------------------------------------------------------
__global__ __launch_bounds__(256) void scan12_kernel(
    const int* __restrict__ deg, int* __restrict__ offL1,
    int* __restrict__ partial, int* __restrict__ partial2,
    int* __restrict__ done) {
  __shared__ int sm[256];
  __shared__ int amLast;
  const int t = threadIdx.x;
  const int i = blockIdx.x * 256 + t;
  const int v = (i < N_NODES) ? deg[i] : 0;
  sm[t] = v;
  __syncthreads();
#pragma unroll
  for (int ofs = 1; ofs < 256; ofs <<= 1) {
    int x = sm[t];
    if (t >= ofs) x += sm[t - ofs];
    __syncthreads();
    sm[t] = x;
    __syncthreads();
  }
  if (i < N_NODES) offL1[i] = sm[t] - v;
  if (t == 255)
    __hip_atomic_store(&partial[blockIdx.x], sm[255], __ATOMIC_RELEASE,
                       __HIP_MEMORY_SCOPE_AGENT);
  __syncthreads();
  if (t == 0) amLast = (atomicAdd(done, 1) == gridDim.x - 1);
  __syncthreads();
  if (amLast) {
    const int pv = (t < NB_SCAN)
                       ? __hip_atomic_load(&partial[t], __ATOMIC_ACQUIRE,
                                           __HIP_MEMORY_SCOPE_AGENT)
                       : 0;
    sm[t] = pv;
    __syncthreads();
#pragma unroll
    for (int ofs = 1; ofs < 256; ofs <<= 1) {
      int x = sm[t];
      if (t >= ofs) x += sm[t - ofs];
      __syncthreads();
      sm[t] = x;
      __syncthreads();
    }
    if (t < NB_SCAN) partial2[t] = sm[t] - pv;  // exclusive
  }
}

// ---------------------------------------------------------------------------
// Atomic-free slot scatter (offsets computed on the fly from offL1+partial2).
// ---------------------------------------------------------------------------
__global__ __launch_bounds__(256) void scatter_kernel(
    const int* __restrict__ ei, const int* __restrict__ offL1,
    const int* __restrict__ partial2, const int* __restrict__ rank,
    int* __restrict__ csr) {
  const int e = (blockIdx.x * 256 + threadIdx.x) * 4;
  if (e + 3 < N_EDGES) {
    const int4 s4 = *(const int4*)(ei + e);
    const int4 d4 = *(const int4*)(ei + N_EDGES + e);
    const int4 r4 = *(const int4*)(rank + e);
    csr[offL1[d4.x] + partial2[d4.x >> 8] + r4.x] = s4.x;
    csr[offL1[d4.y] + partial2[d4.y >> 8] + r4.y] = s4.y;
    csr[offL1[d4.z] + partial2[d4.z >> 8] + r4.z] = s4.z;
    csr[offL1[d4.w] + partial2[d4.w >> 8] + r4.w] = s4.w;
  } else {
    for (int k = e; k < N_EDGES; ++k) {
      const int dst = ei[N_EDGES + k];
      csr[offL1[dst] + partial2[dst >> 8] + rank[k]] = ei[k];
    }
  }
}

// ---------------------------------------------------------------------------
// Mean-aggregate bf16 g rows (permuted layout) per dst node, + r -> out.
// One wave per node; 4 rows per vmem instruction (quarter-wave x uint4).
// Lane c's uint4 chunk holds cols {j*16+c, j=0..7}; epilogue un-permutes.
// ---------------------------------------------------------------------------
#define ACC8(v)                                     \
  do {                                              \
    acc[0] += __uint_as_float((v).x << 16);         \
    acc[1] += __uint_as_float((v).x & 0xffff0000u); \
    acc[2] += __uint_as_float((v).y << 16);         \
    acc[3] += __uint_as_float((v).y & 0xffff0000u); \
    acc[4] += __uint_as_float((v).z << 16);         \
    acc[5] += __uint_as_float((v).z & 0xffff0000u); \
    acc[6] += __uint_as_float((v).w << 16);         \
    acc[7] += __uint_as_float((v).w & 0xffff0000u); \
  } while (0)

__global__ __launch_bounds__(256) void agg_kernel(
    const int* __restrict__ offL1, const int* __restrict__ partial2,
    const int* __restrict__ csr, const unsigned int* __restrict__ gb,
    const float* __restrict__ rp, float* __restrict__ out) {
  const int l = threadIdx.x & 63;
  const int q = l >> 4;  // row within group of 4
  const int c = l & 15;  // 16B chunk within the 256B bf16 row
  const int n = blockIdx.x * 4 + (threadIdx.x >> 6);
  const int s = offL1[n] + partial2[n >> 8];
  const int e = (n + 1 < N_NODES) ? offL1[n + 1] + partial2[(n + 1) >> 8]
                                  : N_EDGES;
  const uint4* g4 = (const uint4*)gb;
  float acc[8];
#pragma unroll
  for (int k = 0; k < 8; ++k) acc[k] = 0.0f;
  for (int base = s; base < e; base += 64) {
    const int cnt = min(e - base, 64);
    int idx = (l < cnt) ? csr[base + l] : 0;
    int j = 0;
    for (; j + 16 <= cnt; j += 16) {
      const int i0 = __shfl(idx, j + 0 + q);
      const int i1 = __shfl(idx, j + 4 + q);
      const int i2 = __shfl(idx, j + 8 + q);
      const int i3 = __shfl(idx, j + 12 + q);
      const uint4 v0 = g4[(size_t)i0 * 16 + c];
      const uint4 v1 = g4[(size_t)i1 * 16 + c];
      const uint4 v2 = g4[(size_t)i2 * 16 + c];
      const uint4 v3 = g4[(size_t)i3 * 16 + c];
      ACC8(v0);
      ACC8(v1);
      ACC8(v2);
      ACC8(v3);
    }
    for (; j + 4 <= cnt; j += 4) {
      const int i0 = __shfl(idx, j + q);
      const uint4 v0 = g4[(size_t)i0 * 16 + c];
      ACC8(v0);
    }
    if (j < cnt) {
      const int rem = cnt - j;  // 1..3 leftover rows
      const int i0 = __shfl(idx, j + min(q, rem - 1));
      if (q < rem) {
        const uint4 v0 = g4[(size_t)i0 * 16 + c];
        ACC8(v0);
      }
    }
  }
#pragma unroll
  for (int k = 0; k < 8; ++k) {
    acc[k] += __shfl_xor(acc[k], 16);
    acc[k] += __shfl_xor(acc[k], 32);
  }
  if (l < 16) {
    const float inv = 1.0f / fmaxf((float)(e - s), 1.0f);
    const float4 rp0 = ((const float4*)rp)[(size_t)n * 32 + c * 2 + 0];
    const float4 rp1 = ((const float4*)rp)[(size_t)n * 32 + c * 2 + 1];
    float* o = out + (size_t)n * D + c;  // col j*16 + c, stride-16 stores
    o[0]   = fmaf(acc[0], inv, rp0.x);
    o[16]  = fmaf(acc[1], inv, rp0.y);
    o[32]  = fmaf(acc[2], inv, rp0.z);
    o[48]  = fmaf(acc[3], inv, rp0.w);
    o[64]  = fmaf(acc[4], inv, rp1.x);
    o[80]  = fmaf(acc[5], inv, rp1.y);
    o[96]  = fmaf(acc[6], inv, rp1.z);
    o[112] = fmaf(acc[7], inv, rp1.w);
  }
}

// ---------------------------------------------------------------------------
extern "C" void kernel_launch(void* const* d_in, const int* in_sizes, int n_in,
                              void* d_out, int out_size, void* d_ws,
                              size_t ws_size, hipStream_t stream) {
  const float* x = (const float*)d_in[0];
  const int* ei = (const int*)d_in[1];  // [2,E] flat: src [0,E), dst [E,2E)
  const float* mask = (const float*)d_in[2];
  const float* gamma = (const float*)d_in[3];
  const float* beta = (const float*)d_in[4];
  const float* w_l = (const float*)d_in[5];
  const float* b_l = (const float*)d_in[6];
  const float* w_r = (const float*)d_in[7];
  float* out = (float*)d_out;

  char* ws = (char*)d_ws;
  size_t off = 0;
  auto alloc = [&](size_t bytes) {
    char* p = ws + off;
    off += (bytes + 255) & ~(size_t)255;
    return p;
  };
  unsigned int* gb =
      (unsigned int*)alloc((size_t)N_NODES * D * sizeof(unsigned short));
  float* rp = (float*)alloc((size_t)N_NODES * D * sizeof(float));
  int* deg = (int*)alloc((size_t)N_NODES * sizeof(int));
  int* offL1 = (int*)alloc((size_t)N_NODES * sizeof(int));
  int* partial = (int*)alloc((size_t)NB_SCAN * sizeof(int));
  int* partial2 = (int*)alloc((size_t)NB_SCAN * sizeof(int));
  int* done = (int*)alloc(sizeof(int));
  int* rank = (int*)alloc((size_t)N_EDGES * sizeof(int));
  int* csr = (int*)alloc((size_t)N_EDGES * sizeof(int));

  zero_kernel<<<NB_SCAN, 256, 0, stream>>>(deg, done);
  gemm_kernel<<<NB_GEMM, 256, 0, stream>>>(x, mask, gamma, beta, w_l, w_r,
                                           b_l, gb, rp, ei, deg, rank);
  scan12_kernel<<<NB_SCAN, 256, 0, stream>>>(deg, offL1, partial, partial2,
                                             done);
  scatter_kernel<<<(N_EDGES / 4 + 255) / 256, 256, 0, stream>>>(
      ei, offL1, partial2, rank, csr);
  agg_kernel<<<N_NODES / 4, 256, 0, stream>>>(offL1, partial2, csr, gb, rp,
                                              out);
}